// Round 21
// baseline (174.548 us; speedup 1.0000x reference)
//
#include <hip/hip_runtime.h>

#define T_STEPS 512
#define BATCH 64

// fp32 casts of np.exp(-1/20), np.exp(-1/5)
__device__ constexpr float ALPHA_ = 0.95122942450071400910f;
__device__ constexpr float BETA_  = 0.81873075307798185867f;

typedef __attribute__((ext_vector_type(8))) short bf16x8;
typedef __attribute__((ext_vector_type(4))) float f32x4;

__device__ inline unsigned short f2bf_rne(float f) {
  union { float f; unsigned int u; } v{f};
  const unsigned int u = v.u;
  return (unsigned short)((u + 0x7FFFu + ((u >> 16) & 1u)) >> 16);
}
__device__ inline float bf2f(unsigned short h) {
  union { unsigned int u; float f; } v{(unsigned int)h << 16};
  return v.f;
}

__device__ inline void gload16(const void* g, void* l) {
  __builtin_amdgcn_global_load_lds(
      (const __attribute__((address_space(1))) unsigned int*)g,
      (__attribute__((address_space(3))) unsigned int*)l, 16, 0, 0);
}

// pack trunc-bf16(first) | trunc-bf16(second)<<16  (exact for spike 0/1)
__device__ inline unsigned int pkbf(float first, float second) {
#if __has_builtin(__builtin_amdgcn_perm)
  return __builtin_amdgcn_perm(__float_as_uint(second), __float_as_uint(first),
                               0x07060302u);
#else
  return (__float_as_uint(first) >> 16) | (__float_as_uint(second) & 0xFFFF0000u);
#endif
}

// 8 fp32 (lo = k0..3, hi = k4..7) -> MFMA bf16x8 fragment word order
__device__ inline bf16x8 cvt_frag(const f32x4 lo, const f32x4 hi) {
  union { unsigned int w[4]; bf16x8 v; } u;
  u.w[0] = pkbf(lo.x, lo.y);
  u.w[1] = pkbf(lo.z, lo.w);
  u.w[2] = pkbf(hi.x, hi.y);
  u.w[3] = pkbf(hi.z, hi.w);
  return u.v;
}

#define SB __builtin_amdgcn_sched_barrier(0)

// ---------------------------------------------------------------------------
// ROLE-INVERTED GEMM0 (R21 experiment): A NEVER touches LDS.
//   A: per-lane fragment gather straight from global into ping-pong REGISTER
//      sets (depth-1; consumed next step; compiler inserts per-wave waits) —
//      the A path has NO ds_read and NO barrier dependency.
//   B: hi/lo bf16 frag-linear in global, staged ONCE per block per step into
//      TRIPLE-buffered LDS via gload_lds (4 instr/thread, depth-2).
//      Counted s_waitcnt vmcnt(8) before the raw s_barrier:
//      queue = [B(kb+1) 4][A(kb+1) 4][B(kb+2) 4] -> completes exactly B(kb+1).
//   BM=64 (2 row-waves x TM=32), BN=128 (2 col-waves), 256 thr,
//   grid (2, 512) = 1024 blocks; LDS 48 KB -> 3 blocks/CU (12 waves/CU).
//   Fragment values and MFMA order identical to R15/R20 -> bit-identical C.
// ---------------------------------------------------------------------------
__global__ __launch_bounds__(256) void gemm_areg(
    const float* __restrict__ A, const char* __restrict__ Bhi,
    const char* __restrict__ Blo, const float* __restrict__ cvec,
    float* __restrict__ C, int N, int K) {
  __shared__ char Bbuf[3][16384];   // [buf][half hi/lo 8KB each]

  const int tid = threadIdx.x;
  const int lane = tid & 63;
  const int wave = tid >> 6;
  const int wm = wave >> 1, wc = wave & 1;
  const int l15 = lane & 15, l4 = lane >> 4;
  const int row0 = blockIdx.y * 64;
  const int col0 = blockIdx.x * 128;
  const int KB = K / 32;

  // A per-lane fragment gather bases (fp32): frag m -> row, k = l4*8
  const float* a_base[2];
#pragma unroll
  for (int m = 0; m < 2; ++m)
    a_base[m] = A + (size_t)(row0 + wm * 32 + m * 16 + l15) * K + l4 * 8;

  // B staging: unit u in [0,512): col-group g=u>>8, inner=u&255.
  // src = (cb0+g)*KB*4096 + kb*4096 + inner*16 ; dst = u*16 (per half).
  const char* bh_src[2];
  const char* bl_src[2];
#pragma unroll
  for (int i = 0; i < 2; ++i) {
    const int u = i * 256 + tid;
    const int g = u >> 8, inner = u & 255;
    const size_t so = ((size_t)(blockIdx.x * 2 + g) * KB) * 4096 + (size_t)inner * 16;
    bh_src[i] = Bhi + so;
    bl_src[i] = Blo + so;
  }

  int boff = 0;
  const int bmax = (KB - 1) * 4096;
  int aoff = 0;
  const int amax = (KB - 1) * 32;   // in floats

  f32x4 acc[2][4] = {};
  // A ping-pong register sets (named, static — rule #20)
  f32x4 aLo0[2], aHi0[2], aLo1[2], aHi1[2];

#define STAGE_B(buf)                                                    \
  do {                                                                  \
    _Pragma("unroll") for (int i = 0; i < 2; ++i) {                     \
      gload16(bh_src[i] + boff, (buf) + (i * 256 + tid) * 16);          \
      gload16(bl_src[i] + boff, (buf) + 8192 + (i * 256 + tid) * 16);   \
    }                                                                   \
  } while (0)

#define LOAD_A(lo_, hi_)                                                \
  do {                                                                  \
    _Pragma("unroll") for (int m = 0; m < 2; ++m) {                     \
      lo_[m] = *(const f32x4*)(a_base[m] + aoff);                       \
      hi_[m] = *(const f32x4*)(a_base[m] + aoff + 4);                   \
    }                                                                   \
  } while (0)

  // ---- prologue: B(0)->buf0; A(0)->set0; B(1)->buf1; vmcnt(8); barrier ----
  SB;
  STAGE_B(Bbuf[0]);                         // B(0)
  SB;
  LOAD_A(aLo0, aHi0);                       // A(0)
  SB;
  boff = 4096;
  STAGE_B(Bbuf[1]);                         // B(1)
  SB;
  boff = (2 * 4096 < bmax) ? 2 * 4096 : bmax;
  aoff = (32 < amax) ? 32 : amax;
  asm volatile("s_waitcnt vmcnt(8)" ::: "memory");  // B(0) landed
  __builtin_amdgcn_s_barrier();
  SB;

#define KSTEP(ALOC, AHIC, ALON, AHIN, BUFC, BUFN2)                           \
  do {                                                                       \
    LOAD_A(ALON, AHIN); /* A(kb+1) */                                        \
    aoff = (aoff < amax) ? aoff + 32 : aoff;                                 \
    SB;                                                                      \
    STAGE_B(BUFN2); /* B(kb+2) */                                            \
    boff = (boff < bmax) ? boff + 4096 : boff;                               \
    SB;                                                                      \
    bf16x8 af[2], bh[4], bl[4];                                              \
    _Pragma("unroll") for (int m = 0; m < 2; ++m)                            \
        af[m] = cvt_frag(ALOC[m], AHIC[m]);                                  \
    _Pragma("unroll") for (int n = 0; n < 4; ++n) {                          \
      bh[n] = *(const bf16x8*)((BUFC) + ((wc * 256 + n * 64 + lane)) * 16);  \
      bl[n] = *(const bf16x8*)((BUFC) + 8192 + ((wc * 256 + n * 64 + lane)) * 16); \
    }                                                                        \
    _Pragma("unroll") for (int m = 0; m < 2; ++m)                            \
      _Pragma("unroll") for (int n = 0; n < 4; ++n) {                        \
        acc[m][n] = __builtin_amdgcn_mfma_f32_16x16x32_bf16(af[m], bh[n],    \
                                                            acc[m][n], 0, 0, 0); \
        acc[m][n] = __builtin_amdgcn_mfma_f32_16x16x32_bf16(af[m], bl[n],    \
                                                            acc[m][n], 0, 0, 0); \
      }                                                                      \
    SB;                                                                      \
    asm volatile("s_waitcnt vmcnt(8)" ::: "memory"); /* B(kb+1) landed */    \
    __builtin_amdgcn_s_barrier();                                            \
    SB;                                                                      \
  } while (0)

  // KB = 32 for L0; loop in pairs with alternating A reg sets and buf rotation
  const int ITER = KB / 2;
  for (int it = 0; it < ITER; ++it) {
    const int kb = it * 2;
    KSTEP(aLo0, aHi0, aLo1, aHi1, Bbuf[kb % 3], Bbuf[(kb + 2) % 3]);
    KSTEP(aLo1, aHi1, aLo0, aHi0, Bbuf[(kb + 1) % 3], Bbuf[(kb + 3) % 3]);
  }
  asm volatile("s_waitcnt vmcnt(0) lgkmcnt(0)" ::: "memory");

#undef KSTEP
#undef LOAD_A
#undef STAGE_B

  // ---- epilogue ----
#pragma unroll
  for (int m = 0; m < 2; ++m) {
    const int rbase = row0 + wm * 32 + m * 16 + l4 * 4;
#pragma unroll
    for (int n = 0; n < 4; ++n) {
      const int c = col0 + wc * 64 + n * 16 + l15;
      const float cc = cvec[c];
#pragma unroll
      for (int r = 0; r < 4; ++r)
        C[(size_t)(rbase + r) * N + c] = acc[m][n][r] + cc;
    }
  }
}

// ---------------------------------------------------------------------------
// R15/R20 deep-pipelined GEMM (layers 1-2). Depth-2 prefetch, triple-buffer
// A LDS via gload_lds, B in compiler-managed ping-pong regs, counted
// vmcnt(AIP+16) before the raw s_barrier completes exactly A(next).
// ---------------------------------------------------------------------------
template <int WM, int WC, int TM, bool LNFOLD>
__global__ __launch_bounds__(256) void gemm_deep2(
    const void* __restrict__ Av, const char* __restrict__ Bhi,
    const char* __restrict__ Blo, const float* __restrict__ uvec,
    const float* __restrict__ cvec, float* __restrict__ C, int N, int K) {
  constexpr int BM = WM * TM;
  constexpr int FM = TM / 16;
  constexpr int ABY = BM * 64;
  constexpr int AIP = ABY / 4096;
  constexpr int ASTEP = 64;
  constexpr int W2N = AIP + 16;
  __shared__ char smem[3 * ABY];

  const int tid = threadIdx.x;
  const int lane = tid & 63;
  const int wave = tid >> 6;
  const int wm = wave / WC, wc = wave % WC;
  const int l15 = lane & 15, l4 = lane >> 4;
  const int row0 = blockIdx.y * BM;
  const int col0 = blockIdx.x * (WC * 64);
  const int KB = K / 32;

  const char* Ab = (const char*)Av;

  const char* a_src[AIP];
#pragma unroll
  for (int i = 0; i < AIP; ++i) {
    const int unit = i * 256 + tid;
    const int r = ((unit >> 6) << 4) | (unit & 15);
    const int j = (unit >> 4) & 3;
    a_src[i] = Ab + ((size_t)(row0 + r) * K + j * 8) * 2;
  }
  const char* bh_base = Bhi + (size_t)(blockIdx.x * WC + wc) * KB * 4096 + (size_t)lane * 16;
  const char* bl_base = Blo + (size_t)(blockIdx.x * WC + wc) * KB * 4096 + (size_t)lane * 16;

  int aoff = 0, boff = 0;
  const int amax = (KB - 1) * ASTEP;
  const int bmax = (KB - 1) * 4096;

  f32x4 acc[FM][4] = {};
  f32x4 acc1[FM] = {};
  const bf16x8 ONES = {0x3F80, 0x3F80, 0x3F80, 0x3F80,
                       0x3F80, 0x3F80, 0x3F80, 0x3F80};
  bf16x8 bh0[4], bl0[4], bh1[4], bl1[4];

#define STAGE_A(buf)                                                   \
  do {                                                                 \
    _Pragma("unroll") for (int i = 0; i < AIP; ++i)                    \
        gload16(a_src[i] + aoff, (buf) + (i * 256 + tid) * 16);        \
  } while (0)

#define LOAD_B(bh, bl, off_)                                           \
  do {                                                                 \
    const char* ph = bh_base + (off_);                                 \
    const char* pl = bl_base + (off_);                                 \
    bh[0] = *(const bf16x8*)(ph);                                      \
    bh[1] = *(const bf16x8*)(ph + 1024);                               \
    bh[2] = *(const bf16x8*)(ph + 2048);                               \
    bh[3] = *(const bf16x8*)(ph + 3072);                               \
    bl[0] = *(const bf16x8*)(pl);                                      \
    bl[1] = *(const bf16x8*)(pl + 1024);                               \
    bl[2] = *(const bf16x8*)(pl + 2048);                               \
    bl[3] = *(const bf16x8*)(pl + 3072);                               \
  } while (0)

  char* bufR = smem;
  char* bufM = smem + ABY;
  char* bufS = smem + 2 * ABY;

  SB;
  STAGE_A(bufR);
  SB;
  LOAD_B(bh0, bl0, 0);
  SB;
  aoff = ASTEP;
  STAGE_A(bufM);
  SB;
  LOAD_B(bh1, bl1, 4096);
  SB;
  aoff = (2 * ASTEP < amax) ? 2 * ASTEP : amax;
  boff = (2 * 4096 < bmax) ? 2 * 4096 : bmax;
  asm volatile("s_waitcnt vmcnt(%0)" ::"i"(W2N) : "memory");
  __builtin_amdgcn_s_barrier();
  SB;

#define KSTEP(BH, BL)                                                        \
  do {                                                                       \
    STAGE_A(bufS);                                                           \
    aoff = (aoff < amax) ? aoff + ASTEP : aoff;                              \
    SB;                                                                      \
    bf16x8 af[FM];                                                           \
    _Pragma("unroll") for (int m = 0; m < FM; ++m) {                         \
      const int fr = wm * FM + m;                                            \
      af[m] = *(const bf16x8*)(bufR + (fr * 64 + lane) * 16);                \
    }                                                                        \
    SB;                                                                      \
    _Pragma("unroll") for (int m = 0; m < FM; ++m) {                         \
      _Pragma("unroll") for (int n = 0; n < 4; ++n) {                        \
        acc[m][n] = __builtin_amdgcn_mfma_f32_16x16x32_bf16(af[m], BH[n],    \
                                                            acc[m][n], 0, 0, 0); \
        acc[m][n] = __builtin_amdgcn_mfma_f32_16x16x32_bf16(af[m], BL[n],    \
                                                            acc[m][n], 0, 0, 0); \
      }                                                                      \
      if constexpr (LNFOLD)                                                  \
        acc1[m] = __builtin_amdgcn_mfma_f32_16x16x32_bf16(af[m], ONES,       \
                                                          acc1[m], 0, 0, 0); \
    }                                                                        \
    SB;                                                                      \
    LOAD_B(BH, BL, boff);                                                    \
    boff = (boff < bmax) ? boff + 4096 : boff;                               \
    SB;                                                                      \
    asm volatile("s_waitcnt vmcnt(%0)" ::"i"(W2N) : "memory");               \
    __builtin_amdgcn_s_barrier();                                            \
    SB;                                                                      \
    { char* t = bufR; bufR = bufM; bufM = bufS; bufS = t; }                  \
  } while (0)

  const int ITER = KB / 2;
  for (int it = 0; it < ITER; ++it) {
    KSTEP(bh0, bl0);
    KSTEP(bh1, bl1);
  }
  asm volatile("s_waitcnt vmcnt(0) lgkmcnt(0)" ::: "memory");

#undef KSTEP
#undef LOAD_B
#undef STAGE_A

  const int row0w = row0 + wm * TM;
  const int col0w = col0 + wc * 64;
#pragma unroll
  for (int m = 0; m < FM; ++m) {
    const int rbase = row0w + m * 16 + l4 * 4;
    float iv[4], mv[4];
    if constexpr (LNFOLD) {
#pragma unroll
      for (int r = 0; r < 4; ++r) {
        const float mean = acc1[m][r] / (float)K;
        const float inv = 1.0f / sqrtf(mean * (1.f - mean) + 1e-6f);
        iv[r] = inv;
        mv[r] = mean * inv;
      }
    }
#pragma unroll
    for (int n = 0; n < 4; ++n) {
      const int c = col0w + n * 16 + l15;
      const float cc = cvec[c];
      float uu = 0.f;
      if constexpr (LNFOLD) uu = uvec[c];
#pragma unroll
      for (int r = 0; r < 4; ++r) {
        float v;
        if constexpr (LNFOLD) v = iv[r] * acc[m][n][r] - mv[r] * uu + cc;
        else v = acc[m][n][r] + cc;
        C[(size_t)(rbase + r) * N + c] = v;
      }
    }
  }
}

// ---------------------------------------------------------------------------
// Prep: W[K,N] f32 (optionally scaled by s[k]) -> split hi/lo bf16 in the
// fragment-linear (64-col-block) global layout consumed by the GEMMs.
// ---------------------------------------------------------------------------
__global__ void prep_split(const float* __restrict__ W, const float* __restrict__ s,
                           char* __restrict__ hi, char* __restrict__ lo,
                           int K, int N) {
  const int g = blockIdx.x * 256 + threadIdx.x;
  const int total = (K * N) / 8;
  if (g >= total) return;
  constexpr int UB = 256;
  const int KB = K / 32;
  const int unit = g % UB;
  const int kb = (g / UB) % KB;
  const int cb = g / (UB * KB);
  const int n = cb * 64 + ((unit >> 6) << 4) + (unit & 15);
  const int kbase = kb * 32 + ((unit >> 4) & 3) * 8;
  short h8[8], l8[8];
#pragma unroll
  for (int jj = 0; jj < 8; ++jj) {
    const int k = kbase + jj;
    float w = W[(size_t)k * N + n];
    if (s) w *= s[k];
    const unsigned short hb = f2bf_rne(w);
    const unsigned short lb = f2bf_rne(w - bf2f(hb));
    h8[jj] = (short)hb;
    l8[jj] = (short)lb;
  }
  *(bf16x8*)(hi + (size_t)g * 16) = *(const bf16x8*)h8;
  *(bf16x8*)(lo + (size_t)g * 16) = *(const bf16x8*)l8;
}

// u[n] = sum_k s[k]*W[k,n];  c[n] = sum_k b[k]*W[k,n] + bias2[n]. Block per n.
__global__ __launch_bounds__(256) void prep_consts(
    const float* __restrict__ W, const float* __restrict__ s,
    const float* __restrict__ b, const float* __restrict__ bias2,
    float* __restrict__ u, float* __restrict__ c, int K, int N) {
  const int n = blockIdx.x;
  const int t = threadIdx.x;
  float us = 0.f, cs = 0.f;
  for (int k = t; k < K; k += 256) {
    const float w = W[(size_t)k * N + n];
    us += s[k] * w;
    cs += b[k] * w;
  }
  __shared__ float su[256], sc[256];
  su[t] = us;
  sc[t] = cs;
  __syncthreads();
  for (int o = 128; o > 0; o >>= 1) {
    if (t < o) { su[t] += su[t + o]; sc[t] += sc[t + o]; }
    __syncthreads();
  }
  if (t == 0) { u[n] = su[0]; c[n] = sc[0] + bias2[n]; }
}

// ---------------------------------------------------------------------------
// LIF scan over T, one thread per (b,h); fp32 currents -> bf16 spikes and/or
// per-(b,h) spike counts. UNROLL=128.
// ---------------------------------------------------------------------------
template <int H, bool SPIKE_OUT, bool ACCUM>
__global__ void lif_scan(const float* __restrict__ xt,
                         unsigned short* __restrict__ sp,
                         float* __restrict__ tsum) {
  const int n = blockIdx.x * 64 + threadIdx.x;
  const int b = n / H, h = n % H;
  const float* p = xt + (size_t)b * T_STEPS * H + h;
  unsigned short* q = nullptr;
  if constexpr (SPIKE_OUT) q = sp + (size_t)b * T_STEPS * H + h;

  float v = 0.f, cur = 0.f, ts = 0.f;
  for (int t = 0; t < T_STEPS; t += 128) {
    float x[128];
#pragma unroll
    for (int u = 0; u < 128; ++u) x[u] = p[(size_t)u * H];
#pragma unroll
    for (int u = 0; u < 128; ++u) {
      cur = BETA_ * cur + x[u];
      v = ALPHA_ * v + cur;
      const bool sb = (v >= 1.f);
      if constexpr (SPIKE_OUT) q[(size_t)u * H] = sb ? 0x3F80 : 0;
      if constexpr (ACCUM) ts += sb ? 1.f : 0.f;
      v = sb ? 0.f : v;
    }
    p += (size_t)128 * H;
    if constexpr (SPIKE_OUT) q += (size_t)128 * H;
  }
  if constexpr (ACCUM) tsum[n] = ts;
}

__global__ void finalize(const float* __restrict__ tsum,
                         const float* __restrict__ Wc,
                         const float* __restrict__ bc,
                         float* __restrict__ out) {
  const int b = threadIdx.x;  // 64 threads, one wave
  float s = 0.f;
#pragma unroll 8
  for (int h = 0; h < 64; ++h) s += tsum[b * 64 + h];
  const float pooled = s * (1.0f / (512.f * 64.f));
  out[2 + b] = pooled;

  float tot = pooled;
  float l0 = pooled * Wc[b * 2 + 0];
  float l1 = pooled * Wc[b * 2 + 1];
#pragma unroll
  for (int off = 32; off > 0; off >>= 1) {
    tot += __shfl_xor(tot, off);
    l0 += __shfl_xor(l0, off);
    l1 += __shfl_xor(l1, off);
  }
  if (b == 0) {
    out[0] = l0 + bc[0];
    out[1] = l1 + bc[1];
    out[66] = tot * (1.0f / 64.f);
  }
}

extern "C" void kernel_launch(void* const* d_in, const int* in_sizes, int n_in,
                              void* d_out, int out_size, void* d_ws, size_t ws_size,
                              hipStream_t stream) {
  const float* X    = (const float*)d_in[0];   // [64,512,64,16] -> [32768,1024]
  const float* W0   = (const float*)d_in[1];   // [1024,256]
  const float* b0   = (const float*)d_in[2];
  const float* W1   = (const float*)d_in[3];   // [256,128]
  const float* b1   = (const float*)d_in[4];
  const float* W2   = (const float*)d_in[5];   // [128,64]
  const float* b2   = (const float*)d_in[6];
  const float* ln1s = (const float*)d_in[7];
  const float* ln1b = (const float*)d_in[8];
  const float* ln2s = (const float*)d_in[9];
  const float* ln2b = (const float*)d_in[10];
  const float* Wc   = (const float*)d_in[11];  // [64,2]
  const float* bc   = (const float*)d_in[12];
  float* out = (float*)d_out;

  char* w = (char*)d_ws;
  float* buf0 = (float*)w;                       // [32768,256] f32 = 33554432 B
  float* buf1 = (float*)w;                       // alias: buf0 dead after scan0
  float* buf2 = (float*)(w + 16777216);          // [32768,64] f32, after buf1
  size_t off = 33554432;
  unsigned short* sp0 = (unsigned short*)(w + off); off += 16777216;  // bf16
  unsigned short* sp1 = (unsigned short*)(w + off); off += 8388608;   // bf16
  char* hi0 = w + off; off += 524288;
  char* lo0 = w + off; off += 524288;
  char* hi1 = w + off; off += 65536;
  char* lo1 = w + off; off += 65536;
  char* hi2 = w + off; off += 16384;
  char* lo2 = w + off; off += 16384;
  float* u1 = (float*)(w + off); off += 512;
  float* c1 = (float*)(w + off); off += 512;
  float* u2 = (float*)(w + off); off += 256;
  float* c2 = (float*)(w + off); off += 256;
  float* tsum = (float*)(w + off); off += 16384;

  const int M = 32768;

  // --- weight prep (frag-linear 64-col-block split hi/lo + LN-fold consts) ---
  prep_split<<<128, 256, 0, stream>>>(W0, nullptr, hi0, lo0, 1024, 256);
  prep_split<<<16, 256, 0, stream>>>(W1, ln1s, hi1, lo1, 256, 128);
  prep_split<<<4, 256, 0, stream>>>(W2, ln2s, hi2, lo2, 128, 64);
  prep_consts<<<128, 256, 0, stream>>>(W1, ln1s, ln1b, b1, u1, c1, 256, 128);
  prep_consts<<<64, 256, 0, stream>>>(W2, ln2s, ln2b, b2, u2, c2, 128, 64);

  // --- layer 0: ROLE-INVERTED GEMM (A in regs, B in LDS). BM=64, BN=128,
  //     grid (2,512) = 1024 blocks, 3 blocks/CU. ---
  gemm_areg<<<dim3(2, M / 64), 256, 0, stream>>>(
      X, hi0, lo0, b0, buf0, 256, 1024);
  lif_scan<256, true, false><<<(BATCH * 256) / 64, 64, 0, stream>>>(buf0, sp0, nullptr);

  // --- layer 1: R20 best (LN folded). BM=64, BN=128, grid (1,512). ---
  gemm_deep2<2, 2, 32, true><<<dim3(1, M / 64), 256, 0, stream>>>(
      sp0, hi1, lo1, u1, c1, buf1, 128, 256);
  lif_scan<128, true, false><<<(BATCH * 128) / 64, 64, 0, stream>>>(buf1, sp1, nullptr);

  // --- layer 2: R20 best. BM=128, BN=64, grid (1,256). ---
  gemm_deep2<4, 1, 32, true><<<dim3(1, M / 128), 256, 0, stream>>>(
      sp1, hi2, lo2, u2, c2, buf2, 64, 128);
  lif_scan<64, false, true><<<(BATCH * 64) / 64, 64, 0, stream>>>(buf2, nullptr, tsum);

  finalize<<<1, 64, 0, stream>>>(tsum, Wc, bc, out);
}

// Round 22
// 125.129 us; speedup vs baseline: 1.3949x; 1.3949x over previous
//
#include <hip/hip_runtime.h>

#define T_STEPS 512
#define BATCH 64

// fp32 casts of np.exp(-1/20), np.exp(-1/5)
__device__ constexpr float ALPHA_ = 0.95122942450071400910f;
__device__ constexpr float BETA_  = 0.81873075307798185867f;

typedef __attribute__((ext_vector_type(8))) short bf16x8;
typedef __attribute__((ext_vector_type(4))) float f32x4;

__device__ inline unsigned short f2bf_rne(float f) {
  union { float f; unsigned int u; } v{f};
  const unsigned int u = v.u;
  return (unsigned short)((u + 0x7FFFu + ((u >> 16) & 1u)) >> 16);
}
__device__ inline float bf2f(unsigned short h) {
  union { unsigned int u; float f; } v{(unsigned int)h << 16};
  return v.f;
}

__device__ inline void gload16(const void* g, void* l) {
  __builtin_amdgcn_global_load_lds(
      (const __attribute__((address_space(1))) unsigned int*)g,
      (__attribute__((address_space(3))) unsigned int*)l, 16, 0, 0);
}

// pack trunc-bf16(first) | trunc-bf16(second)<<16  (exact for spike 0/1)
__device__ inline unsigned int pkbf(float first, float second) {
#if __has_builtin(__builtin_amdgcn_perm)
  return __builtin_amdgcn_perm(__float_as_uint(second), __float_as_uint(first),
                               0x07060302u);
#else
  return (__float_as_uint(first) >> 16) | (__float_as_uint(second) & 0xFFFF0000u);
#endif
}

// 8 fp32 (lo = k0..3, hi = k4..7) -> MFMA bf16x8 fragment word order
__device__ inline bf16x8 cvt_frag(const f32x4 lo, const f32x4 hi) {
  union { unsigned int w[4]; bf16x8 v; } u;
  u.w[0] = pkbf(lo.x, lo.y);
  u.w[1] = pkbf(lo.z, lo.w);
  u.w[2] = pkbf(hi.x, hi.y);
  u.w[3] = pkbf(hi.z, hi.w);
  return u.v;
}

#define SB __builtin_amdgcn_sched_barrier(0)

// ---------------------------------------------------------------------------
// R20 production GEMM (best measured total: 125.5 us). Deep-pipelined,
// depth-2, triple-buffered A LDS via gload_lds, B hi/lo in compiler-managed
// ping-pong regs, counted vmcnt(AIP+16) before the raw s_barrier.
// COAL (A_F32): contiguous 8-rows x 128B staging, chunk-XOR swizzle on
// source AND ds_read (2-way banks, free).
// LNFOLD: rowsum via ones-MFMA; epilogue inv[r]*acc - mi[r]*u[c] + c[c].
// ---------------------------------------------------------------------------
template <int WM, int WC, int TM, bool A_F32, bool LNFOLD, bool COAL>
__global__ __launch_bounds__(256) void gemm_deep2(
    const void* __restrict__ Av, const char* __restrict__ Bhi,
    const char* __restrict__ Blo, const float* __restrict__ uvec,
    const float* __restrict__ cvec, float* __restrict__ C, int N, int K) {
  constexpr int BM = WM * TM;
  constexpr int FM = TM / 16;                      // m-frags per wave
  constexpr int ABY = A_F32 ? BM * 128 : BM * 64;  // A bytes per K-step
  constexpr int AIP = ABY / 4096;                  // A gloads per thread
  constexpr int ASTEP = A_F32 ? 128 : 64;          // A source bytes per kb
  constexpr int W2N = AIP + 16;                    // completes A(next)
  __shared__ char smem[3 * ABY];

  const int tid = threadIdx.x;
  const int lane = tid & 63;
  const int wave = tid >> 6;
  const int wm = wave / WC, wc = wave % WC;
  const int l15 = lane & 15, l4 = lane >> 4;
  const int row0 = blockIdx.y * BM;
  const int col0 = blockIdx.x * (WC * 64);
  const int KB = K / 32;

  const char* Ab = (const char*)Av;

  const char* a_src[AIP];
#pragma unroll
  for (int i = 0; i < AIP; ++i) {
    const int unit = i * 256 + tid;
    if constexpr (A_F32 && COAL) {
      const int r = unit >> 3, c = unit & 7;   // 8 rows x 128B, chunk-swizzled
      a_src[i] = Ab + ((size_t)(row0 + r) * K) * 4 + ((c * 16) ^ ((r & 7) << 4));
    } else if constexpr (A_F32) {
      const int fr = unit >> 7, h = (unit >> 6) & 1, ln = unit & 63;
      a_src[i] = Ab + ((size_t)(row0 + fr * 16 + (ln & 15)) * K + ((ln >> 4) * 8)) * 4 + h * 16;
    } else {
      const int r = ((unit >> 6) << 4) | (unit & 15);
      const int j = (unit >> 4) & 3;
      a_src[i] = Ab + ((size_t)(row0 + r) * K + j * 8) * 2;
    }
  }
  const char* bh_base = Bhi + (size_t)(blockIdx.x * WC + wc) * KB * 4096 + (size_t)lane * 16;
  const char* bl_base = Blo + (size_t)(blockIdx.x * WC + wc) * KB * 4096 + (size_t)lane * 16;

  int aoff = 0, boff = 0;
  const int amax = (KB - 1) * ASTEP;
  const int bmax = (KB - 1) * 4096;

  f32x4 acc[FM][4] = {};
  f32x4 acc1[FM] = {};
  const bf16x8 ONES = {0x3F80, 0x3F80, 0x3F80, 0x3F80,
                       0x3F80, 0x3F80, 0x3F80, 0x3F80};
  bf16x8 bh0[4], bl0[4], bh1[4], bl1[4];

#define STAGE_A(buf)                                                   \
  do {                                                                 \
    _Pragma("unroll") for (int i = 0; i < AIP; ++i)                    \
        gload16(a_src[i] + aoff, (buf) + (i * 256 + tid) * 16);        \
  } while (0)

#define LOAD_B(bh, bl, off_)                                           \
  do {                                                                 \
    const char* ph = bh_base + (off_);                                 \
    const char* pl = bl_base + (off_);                                 \
    bh[0] = *(const bf16x8*)(ph);                                      \
    bh[1] = *(const bf16x8*)(ph + 1024);                               \
    bh[2] = *(const bf16x8*)(ph + 2048);                               \
    bh[3] = *(const bf16x8*)(ph + 3072);                               \
    bl[0] = *(const bf16x8*)(pl);                                      \
    bl[1] = *(const bf16x8*)(pl + 1024);                               \
    bl[2] = *(const bf16x8*)(pl + 2048);                               \
    bl[3] = *(const bf16x8*)(pl + 3072);                               \
  } while (0)

  char* bufR = smem;
  char* bufM = smem + ABY;
  char* bufS = smem + 2 * ABY;

  // ---- prologue ----
  SB;
  STAGE_A(bufR);                      // A(0)
  SB;
  LOAD_B(bh0, bl0, 0);                // B(0)
  SB;
  aoff = ASTEP;
  STAGE_A(bufM);                      // A(1)
  SB;
  LOAD_B(bh1, bl1, 4096);             // B(1)
  SB;
  aoff = (2 * ASTEP < amax) ? 2 * ASTEP : amax;
  boff = (2 * 4096 < bmax) ? 2 * 4096 : bmax;
  asm volatile("s_waitcnt vmcnt(%0)" ::"i"(W2N) : "memory");  // A(0) landed
  __builtin_amdgcn_s_barrier();
  SB;

#define KSTEP(BH, BL)                                                        \
  do {                                                                       \
    STAGE_A(bufS); /* A(kb+2) */                                             \
    aoff = (aoff < amax) ? aoff + ASTEP : aoff;                              \
    SB;                                                                      \
    bf16x8 af[FM];                                                           \
    _Pragma("unroll") for (int m = 0; m < FM; ++m) {                         \
      if constexpr (A_F32 && COAL) {                                         \
        const int rr = wm * TM + m * 16 + l15;                               \
        const int sw = (rr & 7) << 4;                                        \
        const f32x4 lo = *(const f32x4*)(bufR + rr * 128 + ((l4 * 32) ^ sw)); \
        const f32x4 hi = *(const f32x4*)(bufR + rr * 128 + ((l4 * 32 + 16) ^ sw)); \
        af[m] = cvt_frag(lo, hi);                                            \
      } else if constexpr (A_F32) {                                          \
        const int fr = wm * FM + m;                                          \
        const f32x4 lo = *(const f32x4*)(bufR + ((fr * 2 + 0) * 64 + lane) * 16); \
        const f32x4 hi = *(const f32x4*)(bufR + ((fr * 2 + 1) * 64 + lane) * 16); \
        af[m] = cvt_frag(lo, hi);                                            \
      } else {                                                               \
        const int fr = wm * FM + m;                                          \
        af[m] = *(const bf16x8*)(bufR + (fr * 64 + lane) * 16);              \
      }                                                                      \
    }                                                                        \
    SB;                                                                      \
    _Pragma("unroll") for (int m = 0; m < FM; ++m) {                         \
      _Pragma("unroll") for (int n = 0; n < 4; ++n) {                        \
        acc[m][n] = __builtin_amdgcn_mfma_f32_16x16x32_bf16(af[m], BH[n],    \
                                                            acc[m][n], 0, 0, 0); \
        acc[m][n] = __builtin_amdgcn_mfma_f32_16x16x32_bf16(af[m], BL[n],    \
                                                            acc[m][n], 0, 0, 0); \
      }                                                                      \
      if constexpr (LNFOLD)                                                  \
        acc1[m] = __builtin_amdgcn_mfma_f32_16x16x32_bf16(af[m], ONES,       \
                                                          acc1[m], 0, 0, 0); \
    }                                                                        \
    SB;                                                                      \
    LOAD_B(BH, BL, boff); /* B(kb+2) */                                      \
    boff = (boff < bmax) ? boff + 4096 : boff;                               \
    SB;                                                                      \
    asm volatile("s_waitcnt vmcnt(%0)" ::"i"(W2N) : "memory");               \
    __builtin_amdgcn_s_barrier();                                            \
    SB;                                                                      \
    { char* t = bufR; bufR = bufM; bufM = bufS; bufS = t; }                  \
  } while (0)

  const int ITER = KB / 2;
  for (int it = 0; it < ITER; ++it) {
    KSTEP(bh0, bl0);
    KSTEP(bh1, bl1);
  }
  asm volatile("s_waitcnt vmcnt(0) lgkmcnt(0)" ::: "memory");

#undef KSTEP
#undef LOAD_B
#undef STAGE_A

  const int row0w = row0 + wm * TM;
  const int col0w = col0 + wc * 64;
#pragma unroll
  for (int m = 0; m < FM; ++m) {
    const int rbase = row0w + m * 16 + l4 * 4;
    float iv[4], mv[4];
    if constexpr (LNFOLD) {
#pragma unroll
      for (int r = 0; r < 4; ++r) {
        const float mean = acc1[m][r] / (float)K;
        const float inv = 1.0f / sqrtf(mean * (1.f - mean) + 1e-6f);
        iv[r] = inv;
        mv[r] = mean * inv;
      }
    }
#pragma unroll
    for (int n = 0; n < 4; ++n) {
      const int c = col0w + n * 16 + l15;
      const float cc = cvec[c];
      float uu = 0.f;
      if constexpr (LNFOLD) uu = uvec[c];
#pragma unroll
      for (int r = 0; r < 4; ++r) {
        float v;
        if constexpr (LNFOLD) v = iv[r] * acc[m][n][r] - mv[r] * uu + cc;
        else v = acc[m][n][r] + cc;
        C[(size_t)(rbase + r) * N + c] = v;
      }
    }
  }
}

// ---------------------------------------------------------------------------
// Prep: W[K,N] f32 (optionally scaled by s[k]) -> split hi/lo bf16 in the
// fragment-linear (64-col-block) global layout consumed by the GEMMs.
// ---------------------------------------------------------------------------
__global__ void prep_split(const float* __restrict__ W, const float* __restrict__ s,
                           char* __restrict__ hi, char* __restrict__ lo,
                           int K, int N) {
  const int g = blockIdx.x * 256 + threadIdx.x;
  const int total = (K * N) / 8;
  if (g >= total) return;
  constexpr int UB = 256;
  const int KB = K / 32;
  const int unit = g % UB;
  const int kb = (g / UB) % KB;
  const int cb = g / (UB * KB);
  const int n = cb * 64 + ((unit >> 6) << 4) + (unit & 15);
  const int kbase = kb * 32 + ((unit >> 4) & 3) * 8;
  short h8[8], l8[8];
#pragma unroll
  for (int jj = 0; jj < 8; ++jj) {
    const int k = kbase + jj;
    float w = W[(size_t)k * N + n];
    if (s) w *= s[k];
    const unsigned short hb = f2bf_rne(w);
    const unsigned short lb = f2bf_rne(w - bf2f(hb));
    h8[jj] = (short)hb;
    l8[jj] = (short)lb;
  }
  *(bf16x8*)(hi + (size_t)g * 16) = *(const bf16x8*)h8;
  *(bf16x8*)(lo + (size_t)g * 16) = *(const bf16x8*)l8;
}

// u[n] = sum_k s[k]*W[k,n];  c[n] = sum_k b[k]*W[k,n] + bias2[n]. Block per n.
__global__ __launch_bounds__(256) void prep_consts(
    const float* __restrict__ W, const float* __restrict__ s,
    const float* __restrict__ b, const float* __restrict__ bias2,
    float* __restrict__ u, float* __restrict__ c, int K, int N) {
  const int n = blockIdx.x;
  const int t = threadIdx.x;
  float us = 0.f, cs = 0.f;
  for (int k = t; k < K; k += 256) {
    const float w = W[(size_t)k * N + n];
    us += s[k] * w;
    cs += b[k] * w;
  }
  __shared__ float su[256], sc[256];
  su[t] = us;
  sc[t] = cs;
  __syncthreads();
  for (int o = 128; o > 0; o >>= 1) {
    if (t < o) { su[t] += su[t + o]; sc[t] += sc[t + o]; }
    __syncthreads();
  }
  if (t == 0) { u[n] = su[0]; c[n] = sc[0] + bias2[n]; }
}

// ---------------------------------------------------------------------------
// LIF scan over T, one thread per (b,h); fp32 currents -> bf16 spikes and/or
// per-(b,h) spike counts. UNROLL=128 (4 stall windows; scans are 1 wave/CU so
// the 128+ VGPRs are free).
// ---------------------------------------------------------------------------
template <int H, bool SPIKE_OUT, bool ACCUM>
__global__ void lif_scan(const float* __restrict__ xt,
                         unsigned short* __restrict__ sp,
                         float* __restrict__ tsum) {
  const int n = blockIdx.x * 64 + threadIdx.x;
  const int b = n / H, h = n % H;
  const float* p = xt + (size_t)b * T_STEPS * H + h;
  unsigned short* q = nullptr;
  if constexpr (SPIKE_OUT) q = sp + (size_t)b * T_STEPS * H + h;

  float v = 0.f, cur = 0.f, ts = 0.f;
  for (int t = 0; t < T_STEPS; t += 128) {
    float x[128];
#pragma unroll
    for (int u = 0; u < 128; ++u) x[u] = p[(size_t)u * H];
#pragma unroll
    for (int u = 0; u < 128; ++u) {
      cur = BETA_ * cur + x[u];
      v = ALPHA_ * v + cur;
      const bool sb = (v >= 1.f);
      if constexpr (SPIKE_OUT) q[(size_t)u * H] = sb ? 0x3F80 : 0;
      if constexpr (ACCUM) ts += sb ? 1.f : 0.f;
      v = sb ? 0.f : v;
    }
    p += (size_t)128 * H;
    if constexpr (SPIKE_OUT) q += (size_t)128 * H;
  }
  if constexpr (ACCUM) tsum[n] = ts;
}

__global__ void finalize(const float* __restrict__ tsum,
                         const float* __restrict__ Wc,
                         const float* __restrict__ bc,
                         float* __restrict__ out) {
  const int b = threadIdx.x;  // 64 threads, one wave
  float s = 0.f;
#pragma unroll 8
  for (int h = 0; h < 64; ++h) s += tsum[b * 64 + h];
  const float pooled = s * (1.0f / (512.f * 64.f));
  out[2 + b] = pooled;

  float tot = pooled;
  float l0 = pooled * Wc[b * 2 + 0];
  float l1 = pooled * Wc[b * 2 + 1];
#pragma unroll
  for (int off = 32; off > 0; off >>= 1) {
    tot += __shfl_xor(tot, off);
    l0 += __shfl_xor(l0, off);
    l1 += __shfl_xor(l1, off);
  }
  if (b == 0) {
    out[0] = l0 + bc[0];
    out[1] = l1 + bc[1];
    out[66] = tot * (1.0f / 64.f);
  }
}

extern "C" void kernel_launch(void* const* d_in, const int* in_sizes, int n_in,
                              void* d_out, int out_size, void* d_ws, size_t ws_size,
                              hipStream_t stream) {
  const float* X    = (const float*)d_in[0];   // [64,512,64,16] -> [32768,1024]
  const float* W0   = (const float*)d_in[1];   // [1024,256]
  const float* b0   = (const float*)d_in[2];
  const float* W1   = (const float*)d_in[3];   // [256,128]
  const float* b1   = (const float*)d_in[4];
  const float* W2   = (const float*)d_in[5];   // [128,64]
  const float* b2   = (const float*)d_in[6];
  const float* ln1s = (const float*)d_in[7];
  const float* ln1b = (const float*)d_in[8];
  const float* ln2s = (const float*)d_in[9];
  const float* ln2b = (const float*)d_in[10];
  const float* Wc   = (const float*)d_in[11];  // [64,2]
  const float* bc   = (const float*)d_in[12];
  float* out = (float*)d_out;

  char* w = (char*)d_ws;
  float* buf0 = (float*)w;                       // [32768,256] f32 = 33554432 B
  float* buf1 = (float*)w;                       // alias: buf0 dead after scan0
  float* buf2 = (float*)(w + 16777216);          // [32768,64] f32, after buf1
  size_t off = 33554432;
  unsigned short* sp0 = (unsigned short*)(w + off); off += 16777216;  // bf16
  unsigned short* sp1 = (unsigned short*)(w + off); off += 8388608;   // bf16
  char* hi0 = w + off; off += 524288;
  char* lo0 = w + off; off += 524288;
  char* hi1 = w + off; off += 65536;
  char* lo1 = w + off; off += 65536;
  char* hi2 = w + off; off += 16384;
  char* lo2 = w + off; off += 16384;
  float* u1 = (float*)(w + off); off += 512;
  float* c1 = (float*)(w + off); off += 512;
  float* u2 = (float*)(w + off); off += 256;
  float* c2 = (float*)(w + off); off += 256;
  float* tsum = (float*)(w + off); off += 16384;

  const int M = 32768;

  // --- weight prep (frag-linear 64-col-block split hi/lo + LN-fold consts) ---
  prep_split<<<128, 256, 0, stream>>>(W0, nullptr, hi0, lo0, 1024, 256);
  prep_split<<<16, 256, 0, stream>>>(W1, ln1s, hi1, lo1, 256, 128);
  prep_split<<<4, 256, 0, stream>>>(W2, ln2s, hi2, lo2, 128, 64);
  prep_consts<<<128, 256, 0, stream>>>(W1, ln1s, ln1b, b1, u1, c1, 256, 128);
  prep_consts<<<64, 256, 0, stream>>>(W2, ln2s, ln2b, b2, u2, c2, 128, 64);

  // --- layer 0: R20 best (deep2 + COAL). BM=64, BN=256, grid (1,512). ---
  gemm_deep2<1, 4, 64, true, false, true><<<dim3(1, M / 64), 256, 0, stream>>>(
      X, hi0, lo0, nullptr, b0, buf0, 256, 1024);
  lif_scan<256, true, false><<<(BATCH * 256) / 64, 64, 0, stream>>>(buf0, sp0, nullptr);

  // --- layer 1: R20 best (LN folded). BM=64, BN=128, grid (1,512). ---
  gemm_deep2<2, 2, 32, false, true, false><<<dim3(1, M / 64), 256, 0, stream>>>(
      sp0, hi1, lo1, u1, c1, buf1, 128, 256);
  lif_scan<128, true, false><<<(BATCH * 128) / 64, 64, 0, stream>>>(buf1, sp1, nullptr);

  // --- layer 2: R20 best. BM=128, BN=64, grid (1,256). ---
  gemm_deep2<4, 1, 32, false, true, false><<<dim3(1, M / 128), 256, 0, stream>>>(
      sp1, hi2, lo2, u2, c2, buf2, 64, 128);
  lif_scan<64, false, true><<<(BATCH * 64) / 64, 64, 0, stream>>>(buf2, nullptr, tsum);

  finalize<<<1, 64, 0, stream>>>(tsum, Wc, bc, out);
}